// Round 1
// baseline (433.462 us; speedup 1.0000x reference)
//
#include <hip/hip_runtime.h>
#include <hip/hip_bf16.h>

// y[b, i, j] = x[b, i, j-1] + x[b, i, j+1]  — pauli_x matmul collapses to a
// tridiagonal stencil along the last (4096) axis. Pure memory-bound.

#define ROW_LEN   4096
#define ROW_F4    (ROW_LEN / 4)          // 1024 float4 per row

__global__ __launch_bounds__(256) void PauliXGate_50964081934938_kernel(
    const float* __restrict__ x, float* __restrict__ y, long n4) {
    const long stride = (long)gridDim.x * blockDim.x;
    for (long t = (long)blockIdx.x * blockDim.x + threadIdx.x; t < n4; t += stride) {
        const long row = t >> 10;                 // t / ROW_F4
        const int  c4  = (int)(t & (ROW_F4 - 1)); // t % ROW_F4
        const long rowBase = row << 12;           // row * ROW_LEN
        const int  j = c4 << 2;

        const float* __restrict__ xr = x + rowBase;
        const float4 v = *reinterpret_cast<const float4*>(xr + j);
        // Neighbor elements from adjacent float4s — L1/L2 hits (same lines
        // fetched by neighboring lanes). Row boundaries contribute 0.
        const float left  = (c4 > 0)            ? xr[j - 1] : 0.0f;
        const float right = (c4 < ROW_F4 - 1)   ? xr[j + 4] : 0.0f;

        float4 o;
        o.x = left + v.y;
        o.y = v.x  + v.z;
        o.z = v.y  + v.w;
        o.w = v.z  + right;
        *reinterpret_cast<float4*>(y + rowBase + j) = o;
    }
}

extern "C" void kernel_launch(void* const* d_in, const int* in_sizes, int n_in,
                              void* d_out, int out_size, void* d_ws, size_t ws_size,
                              hipStream_t stream) {
    const float* x = (const float*)d_in[0];
    float* y = (float*)d_out;

    const long n4 = (long)out_size / 4;   // total float4s = 16,777,216

    const int block = 256;
    // Memory-bound: cap grid at ~8 blocks/CU × 256 CU and grid-stride the rest.
    long want = (n4 + block - 1) / block;
    int grid = (int)(want < 2048 ? want : 2048);

    PauliXGate_50964081934938_kernel<<<grid, block, 0, stream>>>(x, y, n4);
}